// Round 17
// baseline (147.703 us; speedup 1.0000x reference)
//
#include <hip/hip_runtime.h>
#include <hip/hip_bf16.h>

// GraphSAGE 2-layer forward on MI355X.
// mean(x[src]) @ W == mean((x@W)[src]).
// Pipeline (4 kernels + memset): [pack||partition_fixed] -> [build_both||gemm1]
//   -> [gather1+relu+gemm2] -> [gather2+lsm].
// Round-16: 137.8us; gather_gemm2 dominates (51us, gather phase ~43 + mfma tail).
// This round: unroll-8 row loads in both gathers (more MLP; VGPR headroom 32->~64).

typedef __attribute__((ext_vector_type(8))) short bf16x8;
typedef __attribute__((ext_vector_type(4))) float f32x4;
typedef unsigned int u32;
typedef unsigned short u16;

constexpr int BSHIFT = 9;             // 512 nodes per bucket
constexpr int BNODES = 1 << BSHIFT;
constexpr int CHUNK  = 4096;          // edges per workgroup in partition
constexpr int EPT    = CHUNK / 256;   // 16 edges per thread

__device__ __forceinline__ u16 f2bf(float f) {
    u32 u = __float_as_uint(f);
    return (u16)((u + 0x7fffu + ((u >> 16) & 1u)) >> 16);
}
__device__ __forceinline__ float blo(u32 u) { return __uint_as_float(u << 16); }
__device__ __forceinline__ float bhi(u32 u) { return __uint_as_float(u & 0xffff0000u); }
__device__ __forceinline__ void accp(float2& a, u32 u) { a.x += blo(u); a.y += bhi(u); }
__device__ __forceinline__ u32 pack2(float x, float y) {
    return (u32)f2bf(x) | ((u32)f2bf(y) << 16);
}

// =============== device bodies ===============

__device__ __forceinline__ void pack_body(int bid,
                                          const float* __restrict__ Wl1, const float* __restrict__ Wr1,
                                          const float* __restrict__ Wl2, const float* __restrict__ Wr2,
                                          u16* __restrict__ Pl1, u16* __restrict__ Pr1,
                                          u16* __restrict__ Pl2, u16* __restrict__ Pr2) {
    int u = bid * 256 + threadIdx.x;
    if (u >= 6144) return;
    const float* W; u16* P; int O;
    if (u < 2048)      { W = Wl1; P = Pl1; O = 128; }
    else if (u < 4096) { W = Wr1; P = Pr1; O = 128; u -= 2048; }
    else if (u < 5120) { W = Wl2; P = Pl2; O = 64;  u -= 4096; }
    else               { W = Wr2; P = Pr2; O = 64;  u -= 5120; }
    int lane = u & 63, t = u >> 6;
    int ntiles = O / 16;
    int ks = t / ntiles, nt = t % ntiles;
    int k0 = ks * 32 + (lane >> 4) * 8;
    int col = nt * 16 + (lane & 15);
    bf16x8 o;
#pragma unroll
    for (int j = 0; j < 8; ++j) o[j] = (short)f2bf(W[(size_t)(k0 + j) * O + col]);
    *reinterpret_cast<bf16x8*>(P + (size_t)u * 8) = o;
}

// partition with fixed-capacity buckets: ebuf[bkt*CAP + cursor] = dstLocal<<23|src
__device__ __forceinline__ void partition_body(int b, const int* __restrict__ ei, int E,
                                               int* __restrict__ bcur, u32* __restrict__ ebuf,
                                               int nB, int CAP, int* lds) {
    int* lcnt = lds;
    int* lbase = lds + 1024;
    for (int i = threadIdx.x; i < nB; i += 256) lcnt[i] = 0;
    __syncthreads();
    const int base = b * CHUNK;

    u32 pk[EPT]; int bk[EPT];
#pragma unroll
    for (int k = 0; k < EPT; ++k) {
        int e = base + (int)threadIdx.x + k * 256;
        if (e < E) {
            int s = ei[e], d = ei[E + e];
            bk[k] = d >> BSHIFT;
            pk[k] = ((u32)(d & (BNODES - 1)) << 23) | (u32)s;
            atomicAdd(&lcnt[bk[k]], 1);
        } else bk[k] = -1;
    }
    __syncthreads();
    for (int i = threadIdx.x; i < nB; i += 256) {
        int c = lcnt[i];
        lbase[i] = c ? (CAP * i + atomicAdd(&bcur[i], c)) : 0;
        lcnt[i] = 0;                           // reuse as local cursor
    }
    __syncthreads();
#pragma unroll
    for (int k = 0; k < EPT; ++k) {
        if (bk[k] >= 0) {
            int p = lbase[bk[k]] + atomicAdd(&lcnt[bk[k]], 1);
            ebuf[p] = pk[k];
        }
    }
}

// build (512 thr): bucket -> rowptr (bkt*CAP-based) + deg + csr
__device__ __forceinline__ void build_body512(int bkt, const u32* __restrict__ ebuf,
                                              const int* __restrict__ bcur, int CAP, int n,
                                              int* __restrict__ rowptr, int* __restrict__ deg,
                                              int* __restrict__ csr, int* lds) {
    int* hist   = lds;                 // BNODES
    int* sstart = lds + BNODES;        // BNODES
    int* spart  = lds + 2 * BNODES;    // 8
    const int bb = bkt * CAP;
    const int be = bb + bcur[bkt];
    const int node0 = bkt << BSHIFT;

    for (int i = threadIdx.x; i < BNODES; i += 512) hist[i] = 0;
    __syncthreads();
    for (int e = bb + (int)threadIdx.x; e < be; e += 512)
        atomicAdd(&hist[ebuf[e] >> 23], 1);
    __syncthreads();

    const int t = threadIdx.x;
    const int v = hist[t];
    const int lane = t & 63, wave = t >> 6;   // 8 waves
    int x = v;
#pragma unroll
    for (int off = 1; off < 64; off <<= 1) { int y = __shfl_up(x, off); if (lane >= off) x += y; }
    if (lane == 63) spart[wave] = x;
    __syncthreads();
    int woff = 0;
#pragma unroll
    for (int w = 0; w < 8; ++w) if (w < wave) woff += spart[w];
    const int excl = woff + x - v;
    sstart[t] = excl;
    const int nd = node0 + t;
    if (nd < n) { rowptr[nd] = bb + excl; deg[nd] = v; }
    __syncthreads();
    for (int i = threadIdx.x; i < BNODES; i += 512) hist[i] = 0;   // reuse as cursors
    __syncthreads();

    for (int e = bb + (int)threadIdx.x; e < be; e += 512) {
        u32 pkv = ebuf[e];
        int dl = pkv >> 23;
        int p = atomicAdd(&hist[dl], 1);
        csr[bb + sstart[dl] + p] = (int)(pkv & 0x7FFFFFu);
    }
}

// gemm1 (512 thr, 8 waves x 16 rows): y=x@Py, z=x@Pz+b. Weights LDS-staged.
__device__ __forceinline__ void gemm1_body(int bid, const float* __restrict__ x,
                                           const u16* __restrict__ Py, const u16* __restrict__ Pz,
                                           const float* __restrict__ bias,
                                           u16* __restrict__ yb, u16* __restrict__ zb,
                                           int n, u16* WB /* 32768 u16 = 64KB */) {
    constexpr int STR = 136;
    {
        const uint4* s1 = reinterpret_cast<const uint4*>(Py);
        const uint4* s2 = reinterpret_cast<const uint4*>(Pz);
        uint4* dst = reinterpret_cast<uint4*>(WB);
        for (int i = threadIdx.x; i < 2048; i += 512) dst[i] = s1[i];
        for (int i = threadIdx.x; i < 2048; i += 512) dst[2048 + i] = s2[i];
    }
    __syncthreads();

    const int wave = threadIdx.x >> 6, lane = threadIdx.x & 63;
    const int row0 = bid * 128 + wave * 16;
    const int lr = lane & 15, lg = lane >> 4;
    const bool active = row0 < n;

    f32x4 accy[8], accz[8];
#pragma unroll
    for (int t = 0; t < 8; ++t) { accy[t] = (f32x4){0,0,0,0}; accz[t] = (f32x4){0,0,0,0}; }

    if (active) {
        const int ra = min(row0 + lr, n - 1);
        const float* Ar = x + (size_t)ra * 128;
        float4 A0[4], A1[4];
#pragma unroll
        for (int ks = 0; ks < 4; ++ks) {
            A0[ks] = *reinterpret_cast<const float4*>(Ar + (ks * 4 + lg) * 8);
            A1[ks] = *reinterpret_cast<const float4*>(Ar + (ks * 4 + lg) * 8 + 4);
        }
        const bf16x8* YL = reinterpret_cast<const bf16x8*>(WB) + lane;
        const bf16x8* ZL = YL + 2048;
#pragma unroll
        for (int ks = 0; ks < 4; ++ks) {
            bf16x8 a;
            a[0] = (short)f2bf(A0[ks].x); a[1] = (short)f2bf(A0[ks].y);
            a[2] = (short)f2bf(A0[ks].z); a[3] = (short)f2bf(A0[ks].w);
            a[4] = (short)f2bf(A1[ks].x); a[5] = (short)f2bf(A1[ks].y);
            a[6] = (short)f2bf(A1[ks].z); a[7] = (short)f2bf(A1[ks].w);
#pragma unroll
            for (int t = 0; t < 8; ++t) {
                accy[t] = __builtin_amdgcn_mfma_f32_16x16x32_bf16(a, YL[(ks * 8 + t) * 64], accy[t], 0, 0, 0);
                accz[t] = __builtin_amdgcn_mfma_f32_16x16x32_bf16(a, ZL[(ks * 8 + t) * 64], accz[t], 0, 0, 0);
            }
        }
    }
    __syncthreads();                   // all waves done reading WB -> reuse for epilogue

    if (!active) return;
    u16* L = WB + wave * 16 * STR;     // 8 x 16x136 u16 = 34.8KB <= 64KB
#pragma unroll
    for (int t = 0; t < 8; ++t)
#pragma unroll
        for (int r = 0; r < 4; ++r)
            L[(lg * 4 + r) * STR + t * 16 + lr] = f2bf(accy[t][r]);
#pragma unroll
    for (int it = 0; it < 4; ++it) {
        int idx = it * 64 + lane;
        int row = idx >> 4, c8 = idx & 15;
        if (row0 + row < n)
            *reinterpret_cast<uint4*>(yb + (size_t)(row0 + row) * 128 + c8 * 8) =
                *reinterpret_cast<const uint4*>(&L[row * STR + c8 * 8]);
    }
#pragma unroll
    for (int t = 0; t < 8; ++t) {
        float bv = bias[t * 16 + lr];
#pragma unroll
        for (int r = 0; r < 4; ++r)
            L[(lg * 4 + r) * STR + t * 16 + lr] = f2bf(accz[t][r] + bv);
    }
#pragma unroll
    for (int it = 0; it < 4; ++it) {
        int idx = it * 64 + lane;
        int row = idx >> 4, c8 = idx & 15;
        if (row0 + row < n)
            *reinterpret_cast<uint4*>(zb + (size_t)(row0 + row) * 128 + c8 * 8) =
                *reinterpret_cast<const uint4*>(&L[row * STR + c8 * 8]);
    }
}

// =============== kernels ===============

// weight pack || partition (both layers), fixed-capacity buckets
__global__ __launch_bounds__(256) void pack_part(const float* __restrict__ Wl1, const float* __restrict__ Wr1,
                                                 const float* __restrict__ Wl2, const float* __restrict__ Wr2,
                                                 u16* __restrict__ Pl1, u16* __restrict__ Pr1,
                                                 u16* __restrict__ Pl2, u16* __restrict__ Pr2,
                                                 const int* __restrict__ ei1, int E1, int ng1,
                                                 int* __restrict__ bcur1, u32* __restrict__ eb1,
                                                 const int* __restrict__ ei2, int E2,
                                                 int* __restrict__ bcur2, u32* __restrict__ eb2,
                                                 int nB, int CAP) {
    __shared__ int lds[2048];
    const int b = blockIdx.x;
    if (b < 24) {
        pack_body(b, Wl1, Wr1, Wl2, Wr2, Pl1, Pr1, Pl2, Pr2);
    } else {
        int c = b - 24;
        if (c < ng1) partition_body(c, ei1, E1, bcur1, eb1, nB, CAP, lds);
        else         partition_body(c - ng1, ei2, E2, bcur2, eb2, nB, CAP, lds);
    }
}

// build both CSRs || gemm1 — 512 threads/block, 64KB LDS -> 16 waves/CU.
__global__ __launch_bounds__(512) void build_gemm1(const u32* __restrict__ eb1,
                                                   const int* __restrict__ bcur1,
                                                   int* __restrict__ rp1, int* __restrict__ dg1,
                                                   int* __restrict__ csr1,
                                                   const u32* __restrict__ eb2,
                                                   const int* __restrict__ bcur2,
                                                   int* __restrict__ rp2, int* __restrict__ dg2,
                                                   int* __restrict__ csr2,
                                                   int nB, int CAP, int n,
                                                   const float* __restrict__ x,
                                                   const u16* __restrict__ Py, const u16* __restrict__ Pz,
                                                   const float* __restrict__ bias,
                                                   u16* __restrict__ yb, u16* __restrict__ zb) {
    __shared__ __align__(16) u16 WB[32768];   // 64KB
    const int b = blockIdx.x;
    if (b < nB)           build_body512(b, eb1, bcur1, CAP, n, rp1, dg1, csr1, (int*)WB);
    else if (b < 2 * nB)  build_body512(b - nB, eb2, bcur2, CAP, n, rp2, dg2, csr2, (int*)WB);
    else                  gemm1_body(b - 2 * nB, x, Py, Pz, bias, yb, zb, n, WB);
}

// ---- fused: gather1 + relu + gemm2. 512 threads, 32 nodes/block, unroll-8 gather.
__global__ __launch_bounds__(512) void gather_gemm2(const u16* __restrict__ y1,
                                                    const int* __restrict__ rp1,
                                                    const int* __restrict__ dg1,
                                                    const int* __restrict__ csr1,
                                                    const u16* __restrict__ z1,
                                                    const u16* __restrict__ Pl2,
                                                    const u16* __restrict__ Pr2,
                                                    const float* __restrict__ bias,
                                                    u16* __restrict__ y2, u16* __restrict__ z2,
                                                    int n) {
    constexpr int STR = 136;                   // u16 stride (272 B)
    __shared__ __align__(16) u16 H[32 * STR];  // 17.4 KB
    const int wid = threadIdx.x >> 6, lane = threadIdx.x & 63;
    const int node0 = blockIdx.x * 32;

    // phase 1: each wave gathers 4 nodes (16 lanes/node), relu -> LDS row
    {
        const int l = lane & 15, g = lane >> 4;
        const int lrow = wid * 4 + g;
        const int node = node0 + lrow;
        uint4 o = {0u, 0u, 0u, 0u};
        if (node < n) {
            const int start = rp1[node], end = start + dg1[node];
            float2 a0 = {0,0}, a1 = {0,0}, a2 = {0,0}, a3 = {0,0};
            int e = start;
            for (; e + 8 <= end; e += 8) {
                int s[8];
#pragma unroll
                for (int j = 0; j < 8; ++j) s[j] = csr1[e + j];
                uint4 v[8];
#pragma unroll
                for (int j = 0; j < 8; ++j)
                    v[j] = *reinterpret_cast<const uint4*>(y1 + (size_t)s[j] * 128 + l * 8);
#pragma unroll
                for (int j = 0; j < 8; ++j) {
                    accp(a0, v[j].x); accp(a1, v[j].y); accp(a2, v[j].z); accp(a3, v[j].w);
                }
            }
            for (; e + 4 <= end; e += 4) {
                const int s0 = csr1[e], s1 = csr1[e + 1], s2 = csr1[e + 2], s3 = csr1[e + 3];
                uint4 v0 = *reinterpret_cast<const uint4*>(y1 + (size_t)s0 * 128 + l * 8);
                uint4 v1 = *reinterpret_cast<const uint4*>(y1 + (size_t)s1 * 128 + l * 8);
                uint4 v2 = *reinterpret_cast<const uint4*>(y1 + (size_t)s2 * 128 + l * 8);
                uint4 v3 = *reinterpret_cast<const uint4*>(y1 + (size_t)s3 * 128 + l * 8);
                accp(a0, v0.x); accp(a1, v0.y); accp(a2, v0.z); accp(a3, v0.w);
                accp(a0, v1.x); accp(a1, v1.y); accp(a2, v1.z); accp(a3, v1.w);
                accp(a0, v2.x); accp(a1, v2.y); accp(a2, v2.z); accp(a3, v2.w);
                accp(a0, v3.x); accp(a1, v3.y); accp(a2, v3.z); accp(a3, v3.w);
            }
            for (; e < end; ++e) {
                const int s0 = csr1[e];
                uint4 v0 = *reinterpret_cast<const uint4*>(y1 + (size_t)s0 * 128 + l * 8);
                accp(a0, v0.x); accp(a1, v0.y); accp(a2, v0.z); accp(a3, v0.w);
            }
            const float inv = 1.0f / fmaxf((float)(end - start), 1.0f);
            uint4 zr = *reinterpret_cast<const uint4*>(z1 + (size_t)node * 128 + l * 8);
            o.x = pack2(fmaxf(a0.x * inv + blo(zr.x), 0.f), fmaxf(a0.y * inv + bhi(zr.x), 0.f));
            o.y = pack2(fmaxf(a1.x * inv + blo(zr.y), 0.f), fmaxf(a1.y * inv + bhi(zr.y), 0.f));
            o.z = pack2(fmaxf(a2.x * inv + blo(zr.z), 0.f), fmaxf(a2.y * inv + bhi(zr.z), 0.f));
            o.w = pack2(fmaxf(a3.x * inv + blo(zr.w), 0.f), fmaxf(a3.y * inv + bhi(zr.w), 0.f));
        }
        *reinterpret_cast<uint4*>(&H[lrow * STR + l * 8]) = o;
    }
    __syncthreads();

    // phase 2: this wave's 2 tile-chains. chain k (0..15): m=k&1, c=(k>>1)&3, r=k>>3
    const int l = lane & 15, g = lane >> 4;
    f32x4 acc[2];
    int km[2], kc[2], kr[2];
#pragma unroll
    for (int i = 0; i < 2; ++i) {
        const int k = wid * 2 + i;
        km[i] = k & 1; kc[i] = (k >> 1) & 3; kr[i] = k >> 3;
        acc[i] = (f32x4){0, 0, 0, 0};
        const u16* P = km[i] ? Pr2 : Pl2;
        const bf16x8* B8 = reinterpret_cast<const bf16x8*>(P) + lane;
#pragma unroll
        for (int ks = 0; ks < 4; ++ks) {
            bf16x8 a = *reinterpret_cast<const bf16x8*>(&H[(kr[i] * 16 + l) * STR + ks * 32 + g * 8]);
            acc[i] = __builtin_amdgcn_mfma_f32_16x16x32_bf16(a, B8[(size_t)(ks * 4 + kc[i]) * 64], acc[i], 0, 0, 0);
        }
    }
    __syncthreads();                           // all A-frag reads done -> reuse H

#pragma unroll
    for (int i = 0; i < 2; ++i) {
        const float bv = km[i] ? bias[kc[i] * 16 + l] : 0.f;
#pragma unroll
        for (int j = 0; j < 4; ++j)
            H[(kr[i] * 16 + g * 4 + j) * STR + km[i] * 64 + kc[i] * 16 + l] = f2bf(acc[i][j] + bv);
    }
    __syncthreads();

    {
        const int t = threadIdx.x;
        const int m = t >> 8;                  // 0: y2, 1: z2
        const int idx = t & 255;
        const int row = idx >> 3, c8 = idx & 7;
        if (node0 + row < n) {
            u16* dst = m ? z2 : y2;
            *reinterpret_cast<uint4*>(dst + (size_t)(node0 + row) * 64 + c8 * 8) =
                *reinterpret_cast<const uint4*>(&H[row * STR + m * 64 + c8 * 8]);
        }
    }
}

// gather2 + log_softmax combine (D=64, f32 out). 8 lanes/node, unroll-8.
__global__ __launch_bounds__(256) void gather_lsm(const u16* __restrict__ y,
                                                  const int* __restrict__ rowptr,
                                                  const int* __restrict__ deg,
                                                  const int* __restrict__ csr,
                                                  const u16* __restrict__ z,
                                                  float* __restrict__ out, int n) {
    const int wave = threadIdx.x >> 6, lane = threadIdx.x & 63;
    const int l = lane & 7, g = lane >> 3;            // 8 lanes/node, 8 nodes/wave
    const int node = (blockIdx.x * 4 + wave) * 8 + g;
    const bool ok = node < n;
    int start = 0, end = 0;
    if (ok) { start = rowptr[node]; end = start + deg[node]; }

    float2 a0 = {0,0}, a1 = {0,0}, a2 = {0,0}, a3 = {0,0};
    int e = start;
    for (; e + 8 <= end; e += 8) {
        int s[8];
#pragma unroll
        for (int j = 0; j < 8; ++j) s[j] = csr[e + j];
        uint4 v[8];
#pragma unroll
        for (int j = 0; j < 8; ++j)
            v[j] = *reinterpret_cast<const uint4*>(y + (size_t)s[j] * 64 + l * 8);
#pragma unroll
        for (int j = 0; j < 8; ++j) {
            accp(a0, v[j].x); accp(a1, v[j].y); accp(a2, v[j].z); accp(a3, v[j].w);
        }
    }
    for (; e + 4 <= end; e += 4) {
        const int s0 = csr[e], s1 = csr[e + 1], s2 = csr[e + 2], s3 = csr[e + 3];
        uint4 v0 = *reinterpret_cast<const uint4*>(y + (size_t)s0 * 64 + l * 8);
        uint4 v1 = *reinterpret_cast<const uint4*>(y + (size_t)s1 * 64 + l * 8);
        uint4 v2 = *reinterpret_cast<const uint4*>(y + (size_t)s2 * 64 + l * 8);
        uint4 v3 = *reinterpret_cast<const uint4*>(y + (size_t)s3 * 64 + l * 8);
        accp(a0, v0.x); accp(a1, v0.y); accp(a2, v0.z); accp(a3, v0.w);
        accp(a0, v1.x); accp(a1, v1.y); accp(a2, v1.z); accp(a3, v1.w);
        accp(a0, v2.x); accp(a1, v2.y); accp(a2, v2.z); accp(a3, v2.w);
        accp(a0, v3.x); accp(a1, v3.y); accp(a2, v3.z); accp(a3, v3.w);
    }
    for (; e < end; ++e) {
        const int s0 = csr[e];
        uint4 v0 = *reinterpret_cast<const uint4*>(y + (size_t)s0 * 64 + l * 8);
        accp(a0, v0.x); accp(a1, v0.y); accp(a2, v0.z); accp(a3, v0.w);
    }

    if (ok) {
        const float inv = 1.0f / fmaxf((float)(end - start), 1.0f);
        uint4 zr = *reinterpret_cast<const uint4*>(z + (size_t)node * 64 + l * 8);
        float v0 = a0.x * inv + blo(zr.x), v1 = a0.y * inv + bhi(zr.x);
        float v2 = a1.x * inv + blo(zr.y), v3 = a1.y * inv + bhi(zr.y);
        float v4 = a2.x * inv + blo(zr.z), v5 = a2.y * inv + bhi(zr.z);
        float v6 = a3.x * inv + blo(zr.w), v7 = a3.y * inv + bhi(zr.w);

        float m = fmaxf(fmaxf(fmaxf(v0, v1), fmaxf(v2, v3)), fmaxf(fmaxf(v4, v5), fmaxf(v6, v7)));
        m = fmaxf(m, __shfl_xor(m, 1));
        m = fmaxf(m, __shfl_xor(m, 2));
        m = fmaxf(m, __shfl_xor(m, 4));
        float s = expf(v0 - m) + expf(v1 - m) + expf(v2 - m) + expf(v3 - m) +
                  expf(v4 - m) + expf(v5 - m) + expf(v6 - m) + expf(v7 - m);
        s += __shfl_xor(s, 1);
        s += __shfl_xor(s, 2);
        s += __shfl_xor(s, 4);
        const float c = m + logf(s);
        float* op = out + (size_t)node * 64 + l * 8;
        *reinterpret_cast<float4*>(op)     = (float4){v0 - c, v1 - c, v2 - c, v3 - c};
        *reinterpret_cast<float4*>(op + 4) = (float4){v4 - c, v5 - c, v6 - c, v7 - c};
    }
}

extern "C" void kernel_launch(void* const* d_in, const int* in_sizes, int n_in,
                              void* d_out, int out_size, void* d_ws, size_t ws_size,
                              hipStream_t stream) {
    const float* x    = (const float*)d_in[0];
    const int*   ei1  = (const int*)d_in[1];
    const int*   ei2  = (const int*)d_in[2];
    const float* W_l1 = (const float*)d_in[3];
    const float* b_l1 = (const float*)d_in[4];
    const float* W_r1 = (const float*)d_in[5];
    const float* W_l2 = (const float*)d_in[6];
    const float* b_l2 = (const float*)d_in[7];
    const float* W_r2 = (const float*)d_in[8];

    const int n  = in_sizes[0] / 128;
    const int E1 = in_sizes[1] / 2;
    const int E2 = in_sizes[2] / 2;
    const int nB = (n + BNODES - 1) >> BSHIFT;   // <= 1024
    const int ng1 = (E1 + CHUNK - 1) / CHUNK;
    const int ng2 = (E2 + CHUNK - 1) / CHUNK;
    const int ngp = ng1 + ng2;
    const int Emax = E1 > E2 ? E1 : E2;
    // fixed bucket capacity: 2x mean, rounded up to 1024 (mean~5102 -> 10240; ~70 sigma)
    const int CAP = ((2 * (Emax / nB + 1) + 1023) / 1024) * 1024;

    // ws layout:
    char* w = (char*)d_ws;
    u16* yb  = (u16*)w; w += (size_t)n * 128 * 2;   // y1 = x@Wl1 (bf16)
    u16* zb  = (u16*)w; w += (size_t)n * 128 * 2;   // z1 = x@Wr1 + b1 (bf16)
    u16* y2b = (u16*)w; w += (size_t)n * 64 * 2;    // y2 = h@Wl2
    u16* z2b = (u16*)w; w += (size_t)n * 64 * 2;    // z2 = h@Wr2 + b2
    u16* Pl1 = (u16*)w; w += 16384 * 2;
    u16* Pr1 = (u16*)w; w += 16384 * 2;
    u16* Pl2 = (u16*)w; w += 8192 * 2;
    u16* Pr2 = (u16*)w; w += 8192 * 2;
    int* rp1   = (int*)w; w += (size_t)n * 4;
    int* rp2   = (int*)w; w += (size_t)n * 4;
    int* dg1   = (int*)w; w += (size_t)n * 4;
    int* dg2   = (int*)w; w += (size_t)n * 4;
    int* bcur  = (int*)w; w += 2048 * 4;            // bcur1 | bcur2
    int* csr1  = (int*)w; w += (size_t)nB * CAP * 4;
    int* csr2  = (int*)w; w += (size_t)nB * CAP * 4;
    u32* eb1   = (u32*)w; w += (size_t)nB * CAP * 4;
    u32* eb2   = (u32*)w;

    const int gb128 = (n + 127) / 128;   // gemm1: 128 rows/block (512 thr)

    hipMemsetAsync(bcur, 0, 2048 * sizeof(int), stream);

    // L0: weight pack || partition (fixed-capacity buckets, both layers)
    pack_part<<<24 + ngp, 256, 0, stream>>>(W_l1, W_r1, W_l2, W_r2, Pl1, Pr1, Pl2, Pr2,
                                            ei1, E1, ng1, bcur, eb1,
                                            ei2, E2, bcur + 1024, eb2, nB, CAP);
    // L1: build both CSRs || gemm1 (512 thr, 16 waves/CU at 64KB LDS)
    build_gemm1<<<2 * nB + gb128, 512, 0, stream>>>(eb1, bcur, rp1, dg1, csr1,
                                                    eb2, bcur + 1024, rp2, dg2, csr2,
                                                    nB, CAP, n,
                                                    x, Pl1, Pr1, b_l1, yb, zb);
    // L2: gather1 + relu + gemm2 (512 thr, 32 nodes/block, h in LDS only)
    gather_gemm2<<<(n + 31) / 32, 512, 0, stream>>>(yb, rp1, dg1, csr1, zb, Pl2, Pr2, b_l2,
                                                    y2b, z2b, n);
    // L3: gather2 + log_softmax
    gather_lsm<<<(n + 31) / 32, 256, 0, stream>>>(y2b, rp2, dg2, csr2, z2b, (float*)d_out, n);
}

// Round 18
// 136.969 us; speedup vs baseline: 1.0784x; 1.0784x over previous
//
#include <hip/hip_runtime.h>
#include <hip/hip_bf16.h>

// GraphSAGE 2-layer forward on MI355X.
// mean(x[src]) @ W == mean((x@W)[src]).
// Pipeline (4 kernels + memset): [pack||partition_fixed] -> [build_both||gemm1]
//   -> [gather1+relu+gemm2] -> [gather2+lsm].
// Round-17 lesson: unroll-8 gather regressed (VGPR 32->44, achieved occ 68->38%,
// +10us) — at avg degree 10 the deep unroll trades TLP for unusable MLP.
// This round: clean revert to the round-16 configuration (best: 137.8us).

typedef __attribute__((ext_vector_type(8))) short bf16x8;
typedef __attribute__((ext_vector_type(4))) float f32x4;
typedef unsigned int u32;
typedef unsigned short u16;

constexpr int BSHIFT = 9;             // 512 nodes per bucket
constexpr int BNODES = 1 << BSHIFT;
constexpr int CHUNK  = 4096;          // edges per workgroup in partition
constexpr int EPT    = CHUNK / 256;   // 16 edges per thread

__device__ __forceinline__ u16 f2bf(float f) {
    u32 u = __float_as_uint(f);
    return (u16)((u + 0x7fffu + ((u >> 16) & 1u)) >> 16);
}
__device__ __forceinline__ float blo(u32 u) { return __uint_as_float(u << 16); }
__device__ __forceinline__ float bhi(u32 u) { return __uint_as_float(u & 0xffff0000u); }
__device__ __forceinline__ void accp(float2& a, u32 u) { a.x += blo(u); a.y += bhi(u); }
__device__ __forceinline__ u32 pack2(float x, float y) {
    return (u32)f2bf(x) | ((u32)f2bf(y) << 16);
}

// =============== device bodies ===============

__device__ __forceinline__ void pack_body(int bid,
                                          const float* __restrict__ Wl1, const float* __restrict__ Wr1,
                                          const float* __restrict__ Wl2, const float* __restrict__ Wr2,
                                          u16* __restrict__ Pl1, u16* __restrict__ Pr1,
                                          u16* __restrict__ Pl2, u16* __restrict__ Pr2) {
    int u = bid * 256 + threadIdx.x;
    if (u >= 6144) return;
    const float* W; u16* P; int O;
    if (u < 2048)      { W = Wl1; P = Pl1; O = 128; }
    else if (u < 4096) { W = Wr1; P = Pr1; O = 128; u -= 2048; }
    else if (u < 5120) { W = Wl2; P = Pl2; O = 64;  u -= 4096; }
    else               { W = Wr2; P = Pr2; O = 64;  u -= 5120; }
    int lane = u & 63, t = u >> 6;
    int ntiles = O / 16;
    int ks = t / ntiles, nt = t % ntiles;
    int k0 = ks * 32 + (lane >> 4) * 8;
    int col = nt * 16 + (lane & 15);
    bf16x8 o;
#pragma unroll
    for (int j = 0; j < 8; ++j) o[j] = (short)f2bf(W[(size_t)(k0 + j) * O + col]);
    *reinterpret_cast<bf16x8*>(P + (size_t)u * 8) = o;
}

// partition with fixed-capacity buckets: ebuf[bkt*CAP + cursor] = dstLocal<<23|src
__device__ __forceinline__ void partition_body(int b, const int* __restrict__ ei, int E,
                                               int* __restrict__ bcur, u32* __restrict__ ebuf,
                                               int nB, int CAP, int* lds) {
    int* lcnt = lds;
    int* lbase = lds + 1024;
    for (int i = threadIdx.x; i < nB; i += 256) lcnt[i] = 0;
    __syncthreads();
    const int base = b * CHUNK;

    u32 pk[EPT]; int bk[EPT];
#pragma unroll
    for (int k = 0; k < EPT; ++k) {
        int e = base + (int)threadIdx.x + k * 256;
        if (e < E) {
            int s = ei[e], d = ei[E + e];
            bk[k] = d >> BSHIFT;
            pk[k] = ((u32)(d & (BNODES - 1)) << 23) | (u32)s;
            atomicAdd(&lcnt[bk[k]], 1);
        } else bk[k] = -1;
    }
    __syncthreads();
    for (int i = threadIdx.x; i < nB; i += 256) {
        int c = lcnt[i];
        lbase[i] = c ? (CAP * i + atomicAdd(&bcur[i], c)) : 0;
        lcnt[i] = 0;                           // reuse as local cursor
    }
    __syncthreads();
#pragma unroll
    for (int k = 0; k < EPT; ++k) {
        if (bk[k] >= 0) {
            int p = lbase[bk[k]] + atomicAdd(&lcnt[bk[k]], 1);
            ebuf[p] = pk[k];
        }
    }
}

// build (512 thr): bucket -> rowptr (bkt*CAP-based) + deg + csr
__device__ __forceinline__ void build_body512(int bkt, const u32* __restrict__ ebuf,
                                              const int* __restrict__ bcur, int CAP, int n,
                                              int* __restrict__ rowptr, int* __restrict__ deg,
                                              int* __restrict__ csr, int* lds) {
    int* hist   = lds;                 // BNODES
    int* sstart = lds + BNODES;        // BNODES
    int* spart  = lds + 2 * BNODES;    // 8
    const int bb = bkt * CAP;
    const int be = bb + bcur[bkt];
    const int node0 = bkt << BSHIFT;

    for (int i = threadIdx.x; i < BNODES; i += 512) hist[i] = 0;
    __syncthreads();
    for (int e = bb + (int)threadIdx.x; e < be; e += 512)
        atomicAdd(&hist[ebuf[e] >> 23], 1);
    __syncthreads();

    const int t = threadIdx.x;
    const int v = hist[t];
    const int lane = t & 63, wave = t >> 6;   // 8 waves
    int x = v;
#pragma unroll
    for (int off = 1; off < 64; off <<= 1) { int y = __shfl_up(x, off); if (lane >= off) x += y; }
    if (lane == 63) spart[wave] = x;
    __syncthreads();
    int woff = 0;
#pragma unroll
    for (int w = 0; w < 8; ++w) if (w < wave) woff += spart[w];
    const int excl = woff + x - v;
    sstart[t] = excl;
    const int nd = node0 + t;
    if (nd < n) { rowptr[nd] = bb + excl; deg[nd] = v; }
    __syncthreads();
    for (int i = threadIdx.x; i < BNODES; i += 512) hist[i] = 0;   // reuse as cursors
    __syncthreads();

    for (int e = bb + (int)threadIdx.x; e < be; e += 512) {
        u32 pkv = ebuf[e];
        int dl = pkv >> 23;
        int p = atomicAdd(&hist[dl], 1);
        csr[bb + sstart[dl] + p] = (int)(pkv & 0x7FFFFFu);
    }
}

// gemm1 (512 thr, 8 waves x 16 rows): y=x@Py, z=x@Pz+b. Weights LDS-staged.
__device__ __forceinline__ void gemm1_body(int bid, const float* __restrict__ x,
                                           const u16* __restrict__ Py, const u16* __restrict__ Pz,
                                           const float* __restrict__ bias,
                                           u16* __restrict__ yb, u16* __restrict__ zb,
                                           int n, u16* WB /* 32768 u16 = 64KB */) {
    constexpr int STR = 136;
    {
        const uint4* s1 = reinterpret_cast<const uint4*>(Py);
        const uint4* s2 = reinterpret_cast<const uint4*>(Pz);
        uint4* dst = reinterpret_cast<uint4*>(WB);
        for (int i = threadIdx.x; i < 2048; i += 512) dst[i] = s1[i];
        for (int i = threadIdx.x; i < 2048; i += 512) dst[2048 + i] = s2[i];
    }
    __syncthreads();

    const int wave = threadIdx.x >> 6, lane = threadIdx.x & 63;
    const int row0 = bid * 128 + wave * 16;
    const int lr = lane & 15, lg = lane >> 4;
    const bool active = row0 < n;

    f32x4 accy[8], accz[8];
#pragma unroll
    for (int t = 0; t < 8; ++t) { accy[t] = (f32x4){0,0,0,0}; accz[t] = (f32x4){0,0,0,0}; }

    if (active) {
        const int ra = min(row0 + lr, n - 1);
        const float* Ar = x + (size_t)ra * 128;
        float4 A0[4], A1[4];
#pragma unroll
        for (int ks = 0; ks < 4; ++ks) {
            A0[ks] = *reinterpret_cast<const float4*>(Ar + (ks * 4 + lg) * 8);
            A1[ks] = *reinterpret_cast<const float4*>(Ar + (ks * 4 + lg) * 8 + 4);
        }
        const bf16x8* YL = reinterpret_cast<const bf16x8*>(WB) + lane;
        const bf16x8* ZL = YL + 2048;
#pragma unroll
        for (int ks = 0; ks < 4; ++ks) {
            bf16x8 a;
            a[0] = (short)f2bf(A0[ks].x); a[1] = (short)f2bf(A0[ks].y);
            a[2] = (short)f2bf(A0[ks].z); a[3] = (short)f2bf(A0[ks].w);
            a[4] = (short)f2bf(A1[ks].x); a[5] = (short)f2bf(A1[ks].y);
            a[6] = (short)f2bf(A1[ks].z); a[7] = (short)f2bf(A1[ks].w);
#pragma unroll
            for (int t = 0; t < 8; ++t) {
                accy[t] = __builtin_amdgcn_mfma_f32_16x16x32_bf16(a, YL[(ks * 8 + t) * 64], accy[t], 0, 0, 0);
                accz[t] = __builtin_amdgcn_mfma_f32_16x16x32_bf16(a, ZL[(ks * 8 + t) * 64], accz[t], 0, 0, 0);
            }
        }
    }
    __syncthreads();                   // all waves done reading WB -> reuse for epilogue

    if (!active) return;
    u16* L = WB + wave * 16 * STR;     // 8 x 16x136 u16 = 34.8KB <= 64KB
#pragma unroll
    for (int t = 0; t < 8; ++t)
#pragma unroll
        for (int r = 0; r < 4; ++r)
            L[(lg * 4 + r) * STR + t * 16 + lr] = f2bf(accy[t][r]);
#pragma unroll
    for (int it = 0; it < 4; ++it) {
        int idx = it * 64 + lane;
        int row = idx >> 4, c8 = idx & 15;
        if (row0 + row < n)
            *reinterpret_cast<uint4*>(yb + (size_t)(row0 + row) * 128 + c8 * 8) =
                *reinterpret_cast<const uint4*>(&L[row * STR + c8 * 8]);
    }
#pragma unroll
    for (int t = 0; t < 8; ++t) {
        float bv = bias[t * 16 + lr];
#pragma unroll
        for (int r = 0; r < 4; ++r)
            L[(lg * 4 + r) * STR + t * 16 + lr] = f2bf(accz[t][r] + bv);
    }
#pragma unroll
    for (int it = 0; it < 4; ++it) {
        int idx = it * 64 + lane;
        int row = idx >> 4, c8 = idx & 15;
        if (row0 + row < n)
            *reinterpret_cast<uint4*>(zb + (size_t)(row0 + row) * 128 + c8 * 8) =
                *reinterpret_cast<const uint4*>(&L[row * STR + c8 * 8]);
    }
}

// =============== kernels ===============

// weight pack || partition (both layers), fixed-capacity buckets
__global__ __launch_bounds__(256) void pack_part(const float* __restrict__ Wl1, const float* __restrict__ Wr1,
                                                 const float* __restrict__ Wl2, const float* __restrict__ Wr2,
                                                 u16* __restrict__ Pl1, u16* __restrict__ Pr1,
                                                 u16* __restrict__ Pl2, u16* __restrict__ Pr2,
                                                 const int* __restrict__ ei1, int E1, int ng1,
                                                 int* __restrict__ bcur1, u32* __restrict__ eb1,
                                                 const int* __restrict__ ei2, int E2,
                                                 int* __restrict__ bcur2, u32* __restrict__ eb2,
                                                 int nB, int CAP) {
    __shared__ int lds[2048];
    const int b = blockIdx.x;
    if (b < 24) {
        pack_body(b, Wl1, Wr1, Wl2, Wr2, Pl1, Pr1, Pl2, Pr2);
    } else {
        int c = b - 24;
        if (c < ng1) partition_body(c, ei1, E1, bcur1, eb1, nB, CAP, lds);
        else         partition_body(c - ng1, ei2, E2, bcur2, eb2, nB, CAP, lds);
    }
}

// build both CSRs || gemm1 — 512 threads/block, 64KB LDS -> 16 waves/CU.
__global__ __launch_bounds__(512) void build_gemm1(const u32* __restrict__ eb1,
                                                   const int* __restrict__ bcur1,
                                                   int* __restrict__ rp1, int* __restrict__ dg1,
                                                   int* __restrict__ csr1,
                                                   const u32* __restrict__ eb2,
                                                   const int* __restrict__ bcur2,
                                                   int* __restrict__ rp2, int* __restrict__ dg2,
                                                   int* __restrict__ csr2,
                                                   int nB, int CAP, int n,
                                                   const float* __restrict__ x,
                                                   const u16* __restrict__ Py, const u16* __restrict__ Pz,
                                                   const float* __restrict__ bias,
                                                   u16* __restrict__ yb, u16* __restrict__ zb) {
    __shared__ __align__(16) u16 WB[32768];   // 64KB
    const int b = blockIdx.x;
    if (b < nB)           build_body512(b, eb1, bcur1, CAP, n, rp1, dg1, csr1, (int*)WB);
    else if (b < 2 * nB)  build_body512(b - nB, eb2, bcur2, CAP, n, rp2, dg2, csr2, (int*)WB);
    else                  gemm1_body(b - 2 * nB, x, Py, Pz, bias, yb, zb, n, WB);
}

// ---- fused: gather1 + relu + gemm2. 512 threads, 32 nodes/block.
__global__ __launch_bounds__(512) void gather_gemm2(const u16* __restrict__ y1,
                                                    const int* __restrict__ rp1,
                                                    const int* __restrict__ dg1,
                                                    const int* __restrict__ csr1,
                                                    const u16* __restrict__ z1,
                                                    const u16* __restrict__ Pl2,
                                                    const u16* __restrict__ Pr2,
                                                    const float* __restrict__ bias,
                                                    u16* __restrict__ y2, u16* __restrict__ z2,
                                                    int n) {
    constexpr int STR = 136;                   // u16 stride (272 B)
    __shared__ __align__(16) u16 H[32 * STR];  // 17.4 KB
    const int wid = threadIdx.x >> 6, lane = threadIdx.x & 63;
    const int node0 = blockIdx.x * 32;

    // phase 1: each wave gathers 4 nodes (16 lanes/node), relu -> LDS row
    {
        const int l = lane & 15, g = lane >> 4;
        const int lrow = wid * 4 + g;
        const int node = node0 + lrow;
        uint4 o = {0u, 0u, 0u, 0u};
        if (node < n) {
            const int start = rp1[node], end = start + dg1[node];
            float2 a0 = {0,0}, a1 = {0,0}, a2 = {0,0}, a3 = {0,0};
            int e = start;
            for (; e + 4 <= end; e += 4) {
                const int s0 = csr1[e], s1 = csr1[e + 1], s2 = csr1[e + 2], s3 = csr1[e + 3];
                uint4 v0 = *reinterpret_cast<const uint4*>(y1 + (size_t)s0 * 128 + l * 8);
                uint4 v1 = *reinterpret_cast<const uint4*>(y1 + (size_t)s1 * 128 + l * 8);
                uint4 v2 = *reinterpret_cast<const uint4*>(y1 + (size_t)s2 * 128 + l * 8);
                uint4 v3 = *reinterpret_cast<const uint4*>(y1 + (size_t)s3 * 128 + l * 8);
                accp(a0, v0.x); accp(a1, v0.y); accp(a2, v0.z); accp(a3, v0.w);
                accp(a0, v1.x); accp(a1, v1.y); accp(a2, v1.z); accp(a3, v1.w);
                accp(a0, v2.x); accp(a1, v2.y); accp(a2, v2.z); accp(a3, v2.w);
                accp(a0, v3.x); accp(a1, v3.y); accp(a2, v3.z); accp(a3, v3.w);
            }
            for (; e < end; ++e) {
                const int s0 = csr1[e];
                uint4 v0 = *reinterpret_cast<const uint4*>(y1 + (size_t)s0 * 128 + l * 8);
                accp(a0, v0.x); accp(a1, v0.y); accp(a2, v0.z); accp(a3, v0.w);
            }
            const float inv = 1.0f / fmaxf((float)(end - start), 1.0f);
            uint4 zr = *reinterpret_cast<const uint4*>(z1 + (size_t)node * 128 + l * 8);
            o.x = pack2(fmaxf(a0.x * inv + blo(zr.x), 0.f), fmaxf(a0.y * inv + bhi(zr.x), 0.f));
            o.y = pack2(fmaxf(a1.x * inv + blo(zr.y), 0.f), fmaxf(a1.y * inv + bhi(zr.y), 0.f));
            o.z = pack2(fmaxf(a2.x * inv + blo(zr.z), 0.f), fmaxf(a2.y * inv + bhi(zr.z), 0.f));
            o.w = pack2(fmaxf(a3.x * inv + blo(zr.w), 0.f), fmaxf(a3.y * inv + bhi(zr.w), 0.f));
        }
        *reinterpret_cast<uint4*>(&H[lrow * STR + l * 8]) = o;
    }
    __syncthreads();

    // phase 2: this wave's 2 tile-chains. chain k (0..15): m=k&1, c=(k>>1)&3, r=k>>3
    const int l = lane & 15, g = lane >> 4;
    f32x4 acc[2];
    int km[2], kc[2], kr[2];
#pragma unroll
    for (int i = 0; i < 2; ++i) {
        const int k = wid * 2 + i;
        km[i] = k & 1; kc[i] = (k >> 1) & 3; kr[i] = k >> 3;
        acc[i] = (f32x4){0, 0, 0, 0};
        const u16* P = km[i] ? Pr2 : Pl2;
        const bf16x8* B8 = reinterpret_cast<const bf16x8*>(P) + lane;
#pragma unroll
        for (int ks = 0; ks < 4; ++ks) {
            bf16x8 a = *reinterpret_cast<const bf16x8*>(&H[(kr[i] * 16 + l) * STR + ks * 32 + g * 8]);
            acc[i] = __builtin_amdgcn_mfma_f32_16x16x32_bf16(a, B8[(size_t)(ks * 4 + kc[i]) * 64], acc[i], 0, 0, 0);
        }
    }
    __syncthreads();                           // all A-frag reads done -> reuse H

#pragma unroll
    for (int i = 0; i < 2; ++i) {
        const float bv = km[i] ? bias[kc[i] * 16 + l] : 0.f;
#pragma unroll
        for (int j = 0; j < 4; ++j)
            H[(kr[i] * 16 + g * 4 + j) * STR + km[i] * 64 + kc[i] * 16 + l] = f2bf(acc[i][j] + bv);
    }
    __syncthreads();

    {
        const int t = threadIdx.x;
        const int m = t >> 8;                  // 0: y2, 1: z2
        const int idx = t & 255;
        const int row = idx >> 3, c8 = idx & 7;
        if (node0 + row < n) {
            u16* dst = m ? z2 : y2;
            *reinterpret_cast<uint4*>(dst + (size_t)(node0 + row) * 64 + c8 * 8) =
                *reinterpret_cast<const uint4*>(&H[row * STR + m * 64 + c8 * 8]);
        }
    }
}

// gather2 + log_softmax combine (D=64, f32 out). 8 lanes/node.
__global__ __launch_bounds__(256) void gather_lsm(const u16* __restrict__ y,
                                                  const int* __restrict__ rowptr,
                                                  const int* __restrict__ deg,
                                                  const int* __restrict__ csr,
                                                  const u16* __restrict__ z,
                                                  float* __restrict__ out, int n) {
    const int wave = threadIdx.x >> 6, lane = threadIdx.x & 63;
    const int l = lane & 7, g = lane >> 3;            // 8 lanes/node, 8 nodes/wave
    const int node = (blockIdx.x * 4 + wave) * 8 + g;
    const bool ok = node < n;
    int start = 0, end = 0;
    if (ok) { start = rowptr[node]; end = start + deg[node]; }

    float2 a0 = {0,0}, a1 = {0,0}, a2 = {0,0}, a3 = {0,0};
    int e = start;
    for (; e + 4 <= end; e += 4) {
        const int s0 = csr[e], s1 = csr[e + 1], s2 = csr[e + 2], s3 = csr[e + 3];
        uint4 v0 = *reinterpret_cast<const uint4*>(y + (size_t)s0 * 64 + l * 8);
        uint4 v1 = *reinterpret_cast<const uint4*>(y + (size_t)s1 * 64 + l * 8);
        uint4 v2 = *reinterpret_cast<const uint4*>(y + (size_t)s2 * 64 + l * 8);
        uint4 v3 = *reinterpret_cast<const uint4*>(y + (size_t)s3 * 64 + l * 8);
        accp(a0, v0.x); accp(a1, v0.y); accp(a2, v0.z); accp(a3, v0.w);
        accp(a0, v1.x); accp(a1, v1.y); accp(a2, v1.z); accp(a3, v1.w);
        accp(a0, v2.x); accp(a1, v2.y); accp(a2, v2.z); accp(a3, v2.w);
        accp(a0, v3.x); accp(a1, v3.y); accp(a2, v3.z); accp(a3, v3.w);
    }
    for (; e < end; ++e) {
        const int s0 = csr[e];
        uint4 v0 = *reinterpret_cast<const uint4*>(y + (size_t)s0 * 64 + l * 8);
        accp(a0, v0.x); accp(a1, v0.y); accp(a2, v0.z); accp(a3, v0.w);
    }

    if (ok) {
        const float inv = 1.0f / fmaxf((float)(end - start), 1.0f);
        uint4 zr = *reinterpret_cast<const uint4*>(z + (size_t)node * 64 + l * 8);
        float v0 = a0.x * inv + blo(zr.x), v1 = a0.y * inv + bhi(zr.x);
        float v2 = a1.x * inv + blo(zr.y), v3 = a1.y * inv + bhi(zr.y);
        float v4 = a2.x * inv + blo(zr.z), v5 = a2.y * inv + bhi(zr.z);
        float v6 = a3.x * inv + blo(zr.w), v7 = a3.y * inv + bhi(zr.w);

        float m = fmaxf(fmaxf(fmaxf(v0, v1), fmaxf(v2, v3)), fmaxf(fmaxf(v4, v5), fmaxf(v6, v7)));
        m = fmaxf(m, __shfl_xor(m, 1));
        m = fmaxf(m, __shfl_xor(m, 2));
        m = fmaxf(m, __shfl_xor(m, 4));
        float s = expf(v0 - m) + expf(v1 - m) + expf(v2 - m) + expf(v3 - m) +
                  expf(v4 - m) + expf(v5 - m) + expf(v6 - m) + expf(v7 - m);
        s += __shfl_xor(s, 1);
        s += __shfl_xor(s, 2);
        s += __shfl_xor(s, 4);
        const float c = m + logf(s);
        float* op = out + (size_t)node * 64 + l * 8;
        *reinterpret_cast<float4*>(op)     = (float4){v0 - c, v1 - c, v2 - c, v3 - c};
        *reinterpret_cast<float4*>(op + 4) = (float4){v4 - c, v5 - c, v6 - c, v7 - c};
    }
}

extern "C" void kernel_launch(void* const* d_in, const int* in_sizes, int n_in,
                              void* d_out, int out_size, void* d_ws, size_t ws_size,
                              hipStream_t stream) {
    const float* x    = (const float*)d_in[0];
    const int*   ei1  = (const int*)d_in[1];
    const int*   ei2  = (const int*)d_in[2];
    const float* W_l1 = (const float*)d_in[3];
    const float* b_l1 = (const float*)d_in[4];
    const float* W_r1 = (const float*)d_in[5];
    const float* W_l2 = (const float*)d_in[6];
    const float* b_l2 = (const float*)d_in[7];
    const float* W_r2 = (const float*)d_in[8];

    const int n  = in_sizes[0] / 128;
    const int E1 = in_sizes[1] / 2;
    const int E2 = in_sizes[2] / 2;
    const int nB = (n + BNODES - 1) >> BSHIFT;   // <= 1024
    const int ng1 = (E1 + CHUNK - 1) / CHUNK;
    const int ng2 = (E2 + CHUNK - 1) / CHUNK;
    const int ngp = ng1 + ng2;
    const int Emax = E1 > E2 ? E1 : E2;
    // fixed bucket capacity: 2x mean, rounded up to 1024 (mean~5102 -> 10240; ~70 sigma)
    const int CAP = ((2 * (Emax / nB + 1) + 1023) / 1024) * 1024;

    // ws layout:
    char* w = (char*)d_ws;
    u16* yb  = (u16*)w; w += (size_t)n * 128 * 2;   // y1 = x@Wl1 (bf16)
    u16* zb  = (u16*)w; w += (size_t)n * 128 * 2;   // z1 = x@Wr1 + b1 (bf16)
    u16* y2b = (u16*)w; w += (size_t)n * 64 * 2;    // y2 = h@Wl2
    u16* z2b = (u16*)w; w += (size_t)n * 64 * 2;    // z2 = h@Wr2 + b2
    u16* Pl1 = (u16*)w; w += 16384 * 2;
    u16* Pr1 = (u16*)w; w += 16384 * 2;
    u16* Pl2 = (u16*)w; w += 8192 * 2;
    u16* Pr2 = (u16*)w; w += 8192 * 2;
    int* rp1   = (int*)w; w += (size_t)n * 4;
    int* rp2   = (int*)w; w += (size_t)n * 4;
    int* dg1   = (int*)w; w += (size_t)n * 4;
    int* dg2   = (int*)w; w += (size_t)n * 4;
    int* bcur  = (int*)w; w += 2048 * 4;            // bcur1 | bcur2
    int* csr1  = (int*)w; w += (size_t)nB * CAP * 4;
    int* csr2  = (int*)w; w += (size_t)nB * CAP * 4;
    u32* eb1   = (u32*)w; w += (size_t)nB * CAP * 4;
    u32* eb2   = (u32*)w;

    const int gb128 = (n + 127) / 128;   // gemm1: 128 rows/block (512 thr)

    hipMemsetAsync(bcur, 0, 2048 * sizeof(int), stream);

    // L0: weight pack || partition (fixed-capacity buckets, both layers)
    pack_part<<<24 + ngp, 256, 0, stream>>>(W_l1, W_r1, W_l2, W_r2, Pl1, Pr1, Pl2, Pr2,
                                            ei1, E1, ng1, bcur, eb1,
                                            ei2, E2, bcur + 1024, eb2, nB, CAP);
    // L1: build both CSRs || gemm1 (512 thr, 16 waves/CU at 64KB LDS)
    build_gemm1<<<2 * nB + gb128, 512, 0, stream>>>(eb1, bcur, rp1, dg1, csr1,
                                                    eb2, bcur + 1024, rp2, dg2, csr2,
                                                    nB, CAP, n,
                                                    x, Pl1, Pr1, b_l1, yb, zb);
    // L2: gather1 + relu + gemm2 (512 thr, 32 nodes/block, h in LDS only)
    gather_gemm2<<<(n + 31) / 32, 512, 0, stream>>>(yb, rp1, dg1, csr1, zb, Pl2, Pr2, b_l2,
                                                    y2b, z2b, n);
    // L3: gather2 + log_softmax
    gather_lsm<<<(n + 31) / 32, 256, 0, stream>>>(y2b, rp2, dg2, csr2, z2b, (float*)d_out, n);
}